// Round 5
// baseline (122.180 us; speedup 1.0000x reference)
//
#include <hip/hip_runtime.h>

#define NS 64            // samples = 32 batches * 2 channels
#define HH 640
#define WW 640
#define NPIX (HH * WW)   // 409600
#define TH 320
#define TW 320
#define MINK 10
#define BPS 40           // blocks per sample (16 rows each)
#define TPB 320          // 4 rows x 80 u-slots, 5 waves
#define ITERS 4          // 4 row-steps of 4 rows = 16 rows
#define NWG (NS * BPS)   // 2560 blocks, % 8 == 0

// exact scalar bilinear tap (half-pixel centers, edge clamp) — fallback path only
__device__ __forceinline__ float resize_scalar(const float* __restrict__ tgt, int y, int xc) {
    float sy = fmaxf(0.5f * (float)y - 0.25f, 0.0f);
    int y0 = (int)sy;
    float fy = sy - (float)y0;
    int y1 = min(y0 + 1, TH - 1);
    float sx = fmaxf(0.5f * (float)xc - 0.25f, 0.0f);
    int x0 = (int)sx;
    float fx = sx - (float)x0;
    int x1 = min(x0 + 1, TW - 1);
    const float* r0 = tgt + y0 * TW;
    const float* r1 = tgt + y1 * TW;
    float top = (1.0f - fx) * r0[x0] + fx * r0[x1];
    float bot = (1.0f - fx) * r1[x0] + fx * r1[x1];
    return (1.0f - fy) * top + fy * bot;
}

// ---------------- single fused kernel ----------------
// Phase 1 (all blocks): streaming reduce, transposed partials [BPS][NS].
// Phase 2 (last finished block only): sum partials, OHEM logic, exact top-k
// fallback (histogram select, never triggered when p ~ N/2), final mean.
__global__ __launch_bounds__(TPB) void k_fused(const float* __restrict__ x,
                                               const float* __restrict__ ct,
                                               const float* __restrict__ at,
                                               float* __restrict__ partA,
                                               float* __restrict__ partP,
                                               int* __restrict__ partC,
                                               int* __restrict__ cntS,
                                               int* __restrict__ cntG,
                                               float* __restrict__ out) {
    // bijective XCD swizzle: each XCD gets 320 consecutive work-ids (= 8 samples)
    int orig = blockIdx.x;
    int bid = (orig & 7) * (NWG >> 3) + (orig >> 3);
    int s = bid / BPS, blk = bid % BPS;
    int b = s >> 1, c = s & 1;
    const float* pred = x + (size_t)s * NPIX;
    const float* tgt = (c == 0 ? ct : at) + (size_t)b * (TH * TW);

    int tid = threadIdx.x;
    int u = tid % 80;        // output col group: x = 8u..8u+7
    int rr = tid / 80;       // 0..3
    int rbase = blk * 16;

    // y parity = rr parity (rbase even): fy fixed per thread
    float fy = (rr & 1) ? 0.25f : 0.75f;
    float gy = 1.0f - fy;
    // tgt cols: aligned quad [4u..4u+3] + clamped edge dwords (clamp == resize edge semantics)
    int xq = 4 * u;
    int xl = max(xq - 1, 0);
    int xr = min(xq + 4, TW - 1);

    float sA = 0.0f, sP = 0.0f;
    int cP = 0;

#pragma unroll
    for (int i = 0; i < ITERS; ++i) {
        int y = rbase + rr + 4 * i;
        int y0raw = (y >> 1) + (y & 1) - 1;     // y even: y/2-1 (fy=.75); y odd: (y-1)/2 (fy=.25)
        int y0 = max(y0raw, 0);
        int y1 = min(y0raw + 1, TH - 1);
        const float* r0 = tgt + y0 * TW;
        const float* r1 = tgt + y1 * TW;

        float4 a4 = *reinterpret_cast<const float4*>(r0 + xq);
        float La = r0[xl], Ra = r0[xr];
        float4 b4 = *reinterpret_cast<const float4*>(r1 + xq);
        float Lb = r1[xl], Rb = r1[xr];

        // y-blend 6 source cols
        float mL = gy * La + fy * Lb;
        float m0 = gy * a4.x + fy * b4.x;
        float m1 = gy * a4.y + fy * b4.y;
        float m2 = gy * a4.z + fy * b4.z;
        float m3 = gy * a4.w + fy * b4.w;
        float mR = gy * Ra + fy * Rb;

        // x-interp: out[2j]=0.25*in[j-1]+0.75*in[j]; out[2j+1]=0.75*in[j]+0.25*in[j+1]
        float tv[8];
        tv[0] = 0.25f * mL + 0.75f * m0;
        tv[1] = 0.75f * m0 + 0.25f * m1;
        tv[2] = 0.25f * m0 + 0.75f * m1;
        tv[3] = 0.75f * m1 + 0.25f * m2;
        tv[4] = 0.25f * m1 + 0.75f * m2;
        tv[5] = 0.75f * m2 + 0.25f * m3;
        tv[6] = 0.25f * m2 + 0.75f * m3;
        tv[7] = 0.75f * m3 + 0.25f * mR;

        const float* pr = pred + y * WW + 8 * u;
        float4 p0 = *reinterpret_cast<const float4*>(pr);
        float4 p1 = *reinterpret_cast<const float4*>(pr + 4);
        float pv[8] = {p0.x, p0.y, p0.z, p0.w, p1.x, p1.y, p1.z, p1.w};

#pragma unroll
        for (int j = 0; j < 8; ++j) {
            float d = pv[j] - tv[j];
            float l = d * d;
            sA += l;
            bool pos = tv[j] > 0.0f;
            sP += pos ? l : 0.0f;
            cP += pos ? 1 : 0;
        }
    }

    // wave64 shuffle reduce + LDS block reduce (5 waves)
    for (int off = 32; off > 0; off >>= 1) {
        sA += __shfl_down(sA, off);
        sP += __shfl_down(sP, off);
        cP += __shfl_down(cP, off);
    }
    __shared__ float shA[5], shP[5];
    __shared__ int shC[5];
    int w = tid >> 6;
    if ((tid & 63) == 0) { shA[w] = sA; shP[w] = sP; shC[w] = cP; }
    __syncthreads();

    __shared__ int lastFlag;
    if (tid == 0) {
        float a = 0.0f, p = 0.0f;
        int ci = 0;
        for (int q = 0; q < 5; ++q) { a += shA[q]; p += shP[q]; ci += shC[q]; }
        // transposed layout: finale reads are lane-coalesced
        partA[blk * NS + s] = a;
        partP[blk * NS + s] = p;
        partC[blk * NS + s] = ci;
        __threadfence();                       // release partials to device scope
        int f = 0;
        if (atomicAdd(&cntS[s], 1) == BPS - 1) {   // sample complete
            __threadfence();
            if (atomicAdd(cntG, 1) == NS - 1) f = 1;  // all samples complete
        }
        lastFlag = f;
    }
    __syncthreads();
    if (!lastFlag) return;

    // ---------------- finale: exactly one block reaches here ----------------
    __threadfence();   // acquire: invalidate caches so all partials are visible
    __syncthreads();

    __shared__ float lossSh[NS], topkSh[NS];
    __shared__ int flagSh[NS], pSh[NS];
    if (tid < NS) {
        float a = 0.0f, pp = 0.0f;
        int p = 0;
        for (int q = 0; q < BPS; ++q) {        // coalesced: lane t reads col t
            a  += partA[q * NS + tid];
            pp += partP[q * NS + tid];
            p  += partC[q * NS + tid];
        }
        int k = min((int)((float)p * 3.0f), NPIX - p);  // exact: 3p < 2^24
        pSh[tid] = p;
        topkSh[tid] = 0.0f;
        flagSh[tid] = (k >= MINK && k < NPIX - p) ? 1 : 0;
        float lossv;
        if (k < MINK) {
            lossv = a / (float)NPIX;
        } else {
            float nn = a - pp;                  // sumNeg
            float ts = (k >= NPIX - p) ? nn : 0.0f;  // flagged samples add topk later
            lossv = pp / (float)max(p, 1) + ts / (float)max(k, 1);
        }
        lossSh[tid] = lossv;
    }
    __syncthreads();

    // exact top-k fallback (3-pass bit-histogram select) for flagged samples.
    // Never triggered when p ~ N/2 (k saturates at N-p); kept for correctness.
    __shared__ unsigned int hcnt[2048];
    __shared__ float hsum[2048];
    __shared__ unsigned int selBin, remSh;
    __shared__ float sumTopSh;
    for (int s2 = 0; s2 < NS; ++s2) {
        if (!flagSh[s2]) continue;             // uniform branch
        int p2 = pSh[s2];
        int k2 = min((int)((float)p2 * 3.0f), NPIX - p2);
        const float* pred2 = x + (size_t)s2 * NPIX;
        const float* tgt2 = ((s2 & 1) == 0 ? ct : at) + (size_t)(s2 >> 1) * (TH * TW);
        if (tid == 0) { remSh = (unsigned int)k2; sumTopSh = 0.0f; }
        const int shiftv[3] = {21, 10, 0};
        const unsigned int maskv[3] = {0x7FFu, 0x7FFu, 0x3FFu};
        unsigned int prefix = 0;
        for (int pass = 0; pass < 3; ++pass) {
            for (int i = tid; i < 2048; i += TPB) { hcnt[i] = 0u; hsum[i] = 0.0f; }
            __syncthreads();
            for (int e = tid; e < NPIX; e += TPB) {
                int yy = e / WW, xx = e % WW;
                float tv = resize_scalar(tgt2, yy, xx);
                if (tv > 0.0f) continue;       // positives excluded (-inf in ref)
                float d = pred2[e] - tv;
                float l = d * d;               // >= 0: uint bits order-preserving
                unsigned int bits = __float_as_uint(l);
                bool match;
                if (pass == 0) match = true;
                else if (pass == 1) match = ((bits >> 21) == prefix);
                else match = ((bits >> 10) == prefix);
                if (match) {
                    unsigned int bin = (bits >> shiftv[pass]) & maskv[pass];
                    atomicAdd(&hcnt[bin], 1u);
                    atomicAdd(&hsum[bin], l);
                }
            }
            __syncthreads();
            if (tid == 0) {
                unsigned int remS = remSh;
                int nb = (int)maskv[pass] + 1;
                unsigned int cum = 0; float sAb = 0.0f; unsigned int bsel = 0;
                for (int bin = nb - 1; bin >= 0; --bin) {
                    unsigned int cc = hcnt[bin];
                    if (cum + cc >= remS) { bsel = (unsigned int)bin; break; }
                    cum += cc; sAb += hsum[bin];
                }
                selBin = bsel;
                remSh = remS - cum;
                sumTopSh += sAb;
            }
            __syncthreads();
            if (pass == 0) prefix = selBin;
            else if (pass == 1) prefix = (prefix << 11) | selBin;
            __syncthreads();
        }
        if (tid == 0) {
            unsigned int bits = (prefix << 10) | selBin;   // exact k-th largest
            topkSh[s2] = sumTopSh + (float)remSh * __uint_as_float(bits);
        }
        __syncthreads();
    }

    if (tid < NS) {
        float lossv = lossSh[tid];
        if (flagSh[tid]) {
            int p = pSh[tid];
            int k = min((int)((float)p * 3.0f), NPIX - p);
            lossv += topkSh[tid] / (float)max(k, 1);
        }
        for (int off = 32; off > 0; off >>= 1) lossv += __shfl_down(lossv, off);
        if (tid == 0) out[0] = lossv / 32.0f;   // mean over B of (char + aff)
    }
}

extern "C" void kernel_launch(void* const* d_in, const int* in_sizes, int n_in,
                              void* d_out, int out_size, void* d_ws, size_t ws_size,
                              hipStream_t stream) {
    const float* x  = (const float*)d_in[0];
    const float* ct = (const float*)d_in[1];
    const float* at = (const float*)d_in[2];
    float* out = (float*)d_out;

    float* partA = (float*)d_ws;                 // NWG floats ([BPS][NS])
    float* partP = partA + NWG;                  // NWG floats
    int*   partC = (int*)(partP + NWG);          // NWG ints
    int*   cntS  = partC + NWG;                  // NS ints
    int*   cntG  = cntS + NS;                    // 1 int

    // zero the tickets only (partials fully rewritten every call)
    hipMemsetAsync(cntS, 0, (NS + 1) * sizeof(int), stream);

    k_fused<<<dim3(NWG), dim3(TPB), 0, stream>>>(x, ct, at, partA, partP, partC,
                                                 cntS, cntG, out);
}

// Round 6
// 32.671 us; speedup vs baseline: 3.7397x; 3.7397x over previous
//
#include <hip/hip_runtime.h>

#define NS 64            // samples = 32 batches * 2 channels
#define HH 640
#define WW 640
#define NPIX (HH * WW)   // 409600
#define TH 320
#define TW 320
#define MINK 10
#define BPS 40           // blocks per sample (16 rows each)
#define TPB 320          // 4 rows x 80 u-slots, 5 waves
#define ITERS 4          // 4 row-steps of 4 rows = 16 rows

// exact scalar bilinear tap (half-pixel centers, edge clamp) — fallback path only
__device__ __forceinline__ float resize_scalar(const float* __restrict__ tgt, int y, int xc) {
    float sy = fmaxf(0.5f * (float)y - 0.25f, 0.0f);
    int y0 = (int)sy;
    float fy = sy - (float)y0;
    int y1 = min(y0 + 1, TH - 1);
    float sx = fmaxf(0.5f * (float)xc - 0.25f, 0.0f);
    int x0 = (int)sx;
    float fx = sx - (float)x0;
    int x1 = min(x0 + 1, TW - 1);
    const float* r0 = tgt + y0 * TW;
    const float* r1 = tgt + y1 * TW;
    float top = (1.0f - fx) * r0[x0] + fx * r0[x1];
    float bot = (1.0f - fx) * r1[x0] + fx * r1[x1];
    return (1.0f - fy) * top + fy * bot;
}

// ---------------- pass 1: per-sample streaming reduction (R3-proven) ----------------
__global__ __launch_bounds__(TPB) void k_reduce(const float* __restrict__ x,
                                                const float* __restrict__ ct,
                                                const float* __restrict__ at,
                                                float* __restrict__ partA,
                                                float* __restrict__ partP,
                                                int* __restrict__ partC) {
    int bid = blockIdx.x;
    int s = bid / BPS, blk = bid % BPS;
    int b = s >> 1, c = s & 1;
    const float* pred = x + (size_t)s * NPIX;
    const float* tgt = (c == 0 ? ct : at) + (size_t)b * (TH * TW);

    int tid = threadIdx.x;
    int u = tid % 80;        // output col group: x = 8u..8u+7
    int rr = tid / 80;       // 0..3
    int rbase = blk * 16;

    // y parity = rr parity (rbase even): fy fixed per thread
    float fy = (rr & 1) ? 0.25f : 0.75f;
    float gy = 1.0f - fy;
    // tgt cols: aligned quad [4u..4u+3] + clamped edge dwords (clamp == resize edge semantics)
    int xq = 4 * u;
    int xl = max(xq - 1, 0);
    int xr = min(xq + 4, TW - 1);

    float sA = 0.0f, sP = 0.0f;
    int cP = 0;

#pragma unroll
    for (int i = 0; i < ITERS; ++i) {
        int y = rbase + rr + 4 * i;
        int y0raw = (y >> 1) + (y & 1) - 1;     // y even: y/2-1 (fy=.75); y odd: (y-1)/2 (fy=.25)
        int y0 = max(y0raw, 0);
        int y1 = min(y0raw + 1, TH - 1);
        const float* r0 = tgt + y0 * TW;
        const float* r1 = tgt + y1 * TW;

        float4 a4 = *reinterpret_cast<const float4*>(r0 + xq);
        float La = r0[xl], Ra = r0[xr];
        float4 b4 = *reinterpret_cast<const float4*>(r1 + xq);
        float Lb = r1[xl], Rb = r1[xr];

        // y-blend 6 source cols
        float mL = gy * La + fy * Lb;
        float m0 = gy * a4.x + fy * b4.x;
        float m1 = gy * a4.y + fy * b4.y;
        float m2 = gy * a4.z + fy * b4.z;
        float m3 = gy * a4.w + fy * b4.w;
        float mR = gy * Ra + fy * Rb;

        // x-interp: out[2j]=0.25*in[j-1]+0.75*in[j]; out[2j+1]=0.75*in[j]+0.25*in[j+1]
        float tv[8];
        tv[0] = 0.25f * mL + 0.75f * m0;
        tv[1] = 0.75f * m0 + 0.25f * m1;
        tv[2] = 0.25f * m0 + 0.75f * m1;
        tv[3] = 0.75f * m1 + 0.25f * m2;
        tv[4] = 0.25f * m1 + 0.75f * m2;
        tv[5] = 0.75f * m2 + 0.25f * m3;
        tv[6] = 0.25f * m2 + 0.75f * m3;
        tv[7] = 0.75f * m3 + 0.25f * mR;

        const float* pr = pred + y * WW + 8 * u;
        float4 p0 = *reinterpret_cast<const float4*>(pr);
        float4 p1 = *reinterpret_cast<const float4*>(pr + 4);
        float pv[8] = {p0.x, p0.y, p0.z, p0.w, p1.x, p1.y, p1.z, p1.w};

#pragma unroll
        for (int j = 0; j < 8; ++j) {
            float d = pv[j] - tv[j];
            float l = d * d;
            sA += l;
            bool pos = tv[j] > 0.0f;
            sP += pos ? l : 0.0f;
            cP += pos ? 1 : 0;
        }
    }

    // wave64 shuffle reduce + LDS block reduce (5 waves)
    for (int off = 32; off > 0; off >>= 1) {
        sA += __shfl_down(sA, off);
        sP += __shfl_down(sP, off);
        cP += __shfl_down(cP, off);
    }
    __shared__ float shA[5], shP[5];
    __shared__ int shC[5];
    int w = tid >> 6;
    if ((tid & 63) == 0) { shA[w] = sA; shP[w] = sP; shC[w] = cP; }
    __syncthreads();
    if (tid == 0) {
        float a = 0.0f, p = 0.0f;
        int ci = 0;
        for (int q = 0; q < 5; ++q) { a += shA[q]; p += shP[q]; ci += shC[q]; }
        partA[s * BPS + blk] = a;
        partP[s * BPS + blk] = p;
        partC[s * BPS + blk] = ci;
    }
}

// ---------------- pass 2: single-block tail — sums, OHEM logic, exact
// top-k fallback (never triggered when p ~ N/2, kept for correctness), mean.
__global__ __launch_bounds__(TPB) void k_tail(const float* __restrict__ x,
                                              const float* __restrict__ ct,
                                              const float* __restrict__ at,
                                              const float* __restrict__ partA,
                                              const float* __restrict__ partP,
                                              const int* __restrict__ partC,
                                              float* __restrict__ out) {
    int tid = threadIdx.x;
    __shared__ float lossSh[NS];
    __shared__ int flagSh[NS], pSh[NS];

    if (tid < NS) {
        float a = 0.0f, pp = 0.0f;
        int p = 0;
        const float4* pa4 = reinterpret_cast<const float4*>(partA + tid * BPS);
        const float4* pp4 = reinterpret_cast<const float4*>(partP + tid * BPS);
        const int4*   pc4 = reinterpret_cast<const int4*>(partC + tid * BPS);
#pragma unroll
        for (int q = 0; q < BPS / 4; ++q) {
            float4 va = pa4[q]; a += va.x + va.y + va.z + va.w;
            float4 vp = pp4[q]; pp += vp.x + vp.y + vp.z + vp.w;
            int4 vc = pc4[q]; p += vc.x + vc.y + vc.z + vc.w;
        }
        int k = min((int)((float)p * 3.0f), NPIX - p);  // exact: 3p < 2^24
        pSh[tid] = p;
        flagSh[tid] = (k >= MINK && k < NPIX - p) ? 1 : 0;
        float lossv;
        if (k < MINK) {
            lossv = a / (float)NPIX;
        } else {
            float nn = a - pp;                       // sumNeg
            float ts = (k >= NPIX - p) ? nn : 0.0f;  // flagged samples add topk below
            lossv = pp / (float)max(p, 1) + ts / (float)max(k, 1);
        }
        lossSh[tid] = lossv;
    }
    __syncthreads();

    // exact top-k fallback: 3-pass bit-histogram select over losses of
    // negative-target elements, for any flagged sample (uniform branch).
    __shared__ unsigned int hcnt[2048];
    __shared__ float hsum[2048];
    __shared__ unsigned int selBin, remSh;
    __shared__ float sumTopSh;
    for (int s2 = 0; s2 < NS; ++s2) {
        if (!flagSh[s2]) continue;
        int p2 = pSh[s2];
        int k2 = min((int)((float)p2 * 3.0f), NPIX - p2);
        const float* pred2 = x + (size_t)s2 * NPIX;
        const float* tgt2 = ((s2 & 1) == 0 ? ct : at) + (size_t)(s2 >> 1) * (TH * TW);
        if (tid == 0) { remSh = (unsigned int)k2; sumTopSh = 0.0f; }
        const int shiftv[3] = {21, 10, 0};
        const unsigned int maskv[3] = {0x7FFu, 0x7FFu, 0x3FFu};
        unsigned int prefix = 0;
        for (int pass = 0; pass < 3; ++pass) {
            for (int i = tid; i < 2048; i += TPB) { hcnt[i] = 0u; hsum[i] = 0.0f; }
            __syncthreads();
            for (int e = tid; e < NPIX; e += TPB) {
                int yy = e / WW, xx = e % WW;
                float tv = resize_scalar(tgt2, yy, xx);
                if (tv > 0.0f) continue;       // positives excluded (-inf in ref)
                float d = pred2[e] - tv;
                float l = d * d;               // >= 0: uint bits order-preserving
                unsigned int bits = __float_as_uint(l);
                bool match;
                if (pass == 0) match = true;
                else if (pass == 1) match = ((bits >> 21) == prefix);
                else match = ((bits >> 10) == prefix);
                if (match) {
                    unsigned int bin = (bits >> shiftv[pass]) & maskv[pass];
                    atomicAdd(&hcnt[bin], 1u);
                    atomicAdd(&hsum[bin], l);
                }
            }
            __syncthreads();
            if (tid == 0) {
                unsigned int remS = remSh;
                int nb = (int)maskv[pass] + 1;
                unsigned int cum = 0; float sAb = 0.0f; unsigned int bsel = 0;
                for (int bin = nb - 1; bin >= 0; --bin) {
                    unsigned int cc = hcnt[bin];
                    if (cum + cc >= remS) { bsel = (unsigned int)bin; break; }
                    cum += cc; sAb += hsum[bin];
                }
                selBin = bsel;
                remSh = remS - cum;
                sumTopSh += sAb;
            }
            __syncthreads();
            if (pass == 0) prefix = selBin;
            else if (pass == 1) prefix = (prefix << 11) | selBin;
            __syncthreads();
        }
        if (tid == 0) {
            unsigned int bits = (prefix << 10) | selBin;   // exact k-th largest
            float topk = sumTopSh + (float)remSh * __uint_as_float(bits);
            lossSh[s2] += topk / (float)max(k2, 1);
        }
        __syncthreads();
    }

    if (tid < NS) {
        float lossv = lossSh[tid];
        for (int off = 32; off > 0; off >>= 1) lossv += __shfl_down(lossv, off);
        if (tid == 0) out[0] = lossv / 32.0f;   // mean over B of (char + aff)
    }
}

extern "C" void kernel_launch(void* const* d_in, const int* in_sizes, int n_in,
                              void* d_out, int out_size, void* d_ws, size_t ws_size,
                              hipStream_t stream) {
    const float* x  = (const float*)d_in[0];
    const float* ct = (const float*)d_in[1];
    const float* at = (const float*)d_in[2];
    float* out = (float*)d_out;

    float* partA = (float*)d_ws;                 // NS*BPS floats
    float* partP = partA + NS * BPS;             // NS*BPS floats
    int*   partC = (int*)(partP + NS * BPS);     // NS*BPS ints

    k_reduce<<<dim3(NS * BPS), dim3(TPB), 0, stream>>>(x, ct, at, partA, partP, partC);
    k_tail<<<dim3(1), dim3(TPB), 0, stream>>>(x, ct, at, partA, partP, partC, out);
}

// Round 7
// 32.039 us; speedup vs baseline: 3.8134x; 1.0197x over previous
//
#include <hip/hip_runtime.h>

#define NS 64            // samples = 32 batches * 2 channels
#define HH 640
#define WW 640
#define NPIX (HH * WW)   // 409600
#define TH 320
#define TW 320
#define MINK 10
#define BPS 40           // blocks per sample (16 rows each)
#define TPB 320          // phase A: 1 thread/col; phase B: 4 rows x 80 u-slots
#define LSTR 330         // LDS row stride in floats (bank-swizzle headroom)

__device__ __forceinline__ int swz(int q) { return q + (q >> 5); }

// exact scalar bilinear tap (half-pixel centers, edge clamp) — fallback path only
__device__ __forceinline__ float resize_scalar(const float* __restrict__ tgt, int y, int xc) {
    float sy = fmaxf(0.5f * (float)y - 0.25f, 0.0f);
    int y0 = (int)sy;
    float fy = sy - (float)y0;
    int y1 = min(y0 + 1, TH - 1);
    float sx = fmaxf(0.5f * (float)xc - 0.25f, 0.0f);
    int x0 = (int)sx;
    float fx = sx - (float)x0;
    int x1 = min(x0 + 1, TW - 1);
    const float* r0 = tgt + y0 * TW;
    const float* r1 = tgt + y1 * TW;
    float top = (1.0f - fx) * r0[x0] + fx * r0[x1];
    float bot = (1.0f - fx) * r1[x0] + fx * r1[x1];
    return (1.0f - fy) * top + fy * bot;
}

// ---------------- pass 1: per-sample streaming reduction ----------------
// Phase A: stage+y-blend tgt rows into LDS (dense coalesced loads only).
// Phase B: taps from LDS, pred streamed as float4. Zero scattered VMEM.
__global__ __launch_bounds__(TPB) void k_reduce(const float* __restrict__ x,
                                                const float* __restrict__ ct,
                                                const float* __restrict__ at,
                                                float* __restrict__ partA,
                                                float* __restrict__ partP,
                                                int* __restrict__ partC) {
    int bid = blockIdx.x;
    int s = bid / BPS, blk = bid % BPS;
    int b = s >> 1, c = s & 1;
    const float* pred = x + (size_t)s * NPIX;
    const float* tgt = (c == 0 ? ct : at) + (size_t)b * (TH * TW);

    int tid = threadIdx.x;
    __shared__ float sm[16 * LSTR];   // 16 pre-y-blended rows, swizzled

    // ---- phase A: thread = column; 10 clamped rows -> 16 blended rows ----
    {
        int cc = tid;                 // 0..319
        int h = blk * 8;              // first tgt row index is h-1 (clamped)
        float rowv[10];
#pragma unroll
        for (int r = 0; r < 10; ++r) {
            int ri = min(max(h - 1 + r, 0), TH - 1);   // clamp == resize edge semantics
            rowv[r] = tgt[ri * TW + cc];
        }
        int sc = swz(cc);
#pragma unroll
        for (int j = 0; j < 16; ++j) {
            // output row y=16*blk+j: y0raw=h+(j>>1)+(j&1)-1 -> local l0=(j>>1)+(j&1)
            int l0 = (j >> 1) + (j & 1);
            float fy = (j & 1) ? 0.25f : 0.75f;
            sm[j * LSTR + sc] = (1.0f - fy) * rowv[l0] + fy * rowv[l0 + 1];
        }
    }
    __syncthreads();

    // ---- phase B: u = output col group (8 px), rr+4i = local row ----
    int u = tid % 80, rr = tid / 80;
    int rbase = blk * 16;
    int xq = 4 * u;
    int sL = swz(max(xq - 1, 0));     // clamp: u==0 -> sL==s0 -> pure m0 (correct)
    int s0 = swz(xq);                 // cols 4u..4u+3 never cross a 32-block: s0..s0+3
    int sR = swz(min(xq + 4, TW - 1));// clamp: u==79 -> sR==s0+3 -> pure m3 (correct)

    float sA = 0.0f, sP = 0.0f;
    int cP = 0;

#pragma unroll
    for (int i = 0; i < 4; ++i) {
        int j = rr + 4 * i;
        const float* mr = sm + j * LSTR;
        float mL = mr[sL];
        float m0 = mr[s0];
        float m1 = mr[s0 + 1];
        float m2 = mr[s0 + 2];
        float m3 = mr[s0 + 3];
        float mR = mr[sR];

        // x-interp: out[2t]=0.25*in[t-1]+0.75*in[t]; out[2t+1]=0.75*in[t]+0.25*in[t+1]
        float tv[8];
        tv[0] = 0.25f * mL + 0.75f * m0;
        tv[1] = 0.75f * m0 + 0.25f * m1;
        tv[2] = 0.25f * m0 + 0.75f * m1;
        tv[3] = 0.75f * m1 + 0.25f * m2;
        tv[4] = 0.25f * m1 + 0.75f * m2;
        tv[5] = 0.75f * m2 + 0.25f * m3;
        tv[6] = 0.25f * m2 + 0.75f * m3;
        tv[7] = 0.75f * m3 + 0.25f * mR;

        const float* pr = pred + (rbase + j) * WW + 8 * u;
        float4 p0 = *reinterpret_cast<const float4*>(pr);
        float4 p1 = *reinterpret_cast<const float4*>(pr + 4);
        float pv[8] = {p0.x, p0.y, p0.z, p0.w, p1.x, p1.y, p1.z, p1.w};

#pragma unroll
        for (int t = 0; t < 8; ++t) {
            float d = pv[t] - tv[t];
            float l = d * d;
            sA += l;
            bool pos = tv[t] > 0.0f;
            sP += pos ? l : 0.0f;
            cP += pos ? 1 : 0;
        }
    }

    // wave64 shuffle reduce + LDS block reduce (5 waves)
    for (int off = 32; off > 0; off >>= 1) {
        sA += __shfl_down(sA, off);
        sP += __shfl_down(sP, off);
        cP += __shfl_down(cP, off);
    }
    __shared__ float shA[5], shP[5];
    __shared__ int shC[5];
    int w = tid >> 6;
    if ((tid & 63) == 0) { shA[w] = sA; shP[w] = sP; shC[w] = cP; }
    __syncthreads();
    if (tid == 0) {
        float a = 0.0f, p = 0.0f;
        int ci = 0;
        for (int q = 0; q < 5; ++q) { a += shA[q]; p += shP[q]; ci += shC[q]; }
        partA[s * BPS + blk] = a;
        partP[s * BPS + blk] = p;
        partC[s * BPS + blk] = ci;
    }
}

// ---------------- pass 2: single-block tail — sums, OHEM logic, exact
// top-k fallback (never triggered when p ~ N/2, kept for correctness), mean.
__global__ __launch_bounds__(TPB) void k_tail(const float* __restrict__ x,
                                              const float* __restrict__ ct,
                                              const float* __restrict__ at,
                                              const float* __restrict__ partA,
                                              const float* __restrict__ partP,
                                              const int* __restrict__ partC,
                                              float* __restrict__ out) {
    int tid = threadIdx.x;
    __shared__ float lossSh[NS];
    __shared__ int flagSh[NS], pSh[NS];

    if (tid < NS) {
        float a = 0.0f, pp = 0.0f;
        int p = 0;
        const float4* pa4 = reinterpret_cast<const float4*>(partA + tid * BPS);
        const float4* pp4 = reinterpret_cast<const float4*>(partP + tid * BPS);
        const int4*   pc4 = reinterpret_cast<const int4*>(partC + tid * BPS);
#pragma unroll
        for (int q = 0; q < BPS / 4; ++q) {
            float4 va = pa4[q]; a += va.x + va.y + va.z + va.w;
            float4 vp = pp4[q]; pp += vp.x + vp.y + vp.z + vp.w;
            int4 vc = pc4[q]; p += vc.x + vc.y + vc.z + vc.w;
        }
        int k = min((int)((float)p * 3.0f), NPIX - p);  // exact: 3p < 2^24
        pSh[tid] = p;
        flagSh[tid] = (k >= MINK && k < NPIX - p) ? 1 : 0;
        float lossv;
        if (k < MINK) {
            lossv = a / (float)NPIX;
        } else {
            float nn = a - pp;                       // sumNeg
            float ts = (k >= NPIX - p) ? nn : 0.0f;  // flagged samples add topk below
            lossv = pp / (float)max(p, 1) + ts / (float)max(k, 1);
        }
        lossSh[tid] = lossv;
    }
    __syncthreads();

    // exact top-k fallback: 3-pass bit-histogram select over losses of
    // negative-target elements, for any flagged sample (uniform branch).
    __shared__ unsigned int hcnt[2048];
    __shared__ float hsum[2048];
    __shared__ unsigned int selBin, remSh;
    __shared__ float sumTopSh;
    for (int s2 = 0; s2 < NS; ++s2) {
        if (!flagSh[s2]) continue;
        int p2 = pSh[s2];
        int k2 = min((int)((float)p2 * 3.0f), NPIX - p2);
        const float* pred2 = x + (size_t)s2 * NPIX;
        const float* tgt2 = ((s2 & 1) == 0 ? ct : at) + (size_t)(s2 >> 1) * (TH * TW);
        if (tid == 0) { remSh = (unsigned int)k2; sumTopSh = 0.0f; }
        const int shiftv[3] = {21, 10, 0};
        const unsigned int maskv[3] = {0x7FFu, 0x7FFu, 0x3FFu};
        unsigned int prefix = 0;
        for (int pass = 0; pass < 3; ++pass) {
            for (int i = tid; i < 2048; i += TPB) { hcnt[i] = 0u; hsum[i] = 0.0f; }
            __syncthreads();
            for (int e = tid; e < NPIX; e += TPB) {
                int yy = e / WW, xx = e % WW;
                float tv = resize_scalar(tgt2, yy, xx);
                if (tv > 0.0f) continue;       // positives excluded (-inf in ref)
                float d = pred2[e] - tv;
                float l = d * d;               // >= 0: uint bits order-preserving
                unsigned int bits = __float_as_uint(l);
                bool match;
                if (pass == 0) match = true;
                else if (pass == 1) match = ((bits >> 21) == prefix);
                else match = ((bits >> 10) == prefix);
                if (match) {
                    unsigned int bin = (bits >> shiftv[pass]) & maskv[pass];
                    atomicAdd(&hcnt[bin], 1u);
                    atomicAdd(&hsum[bin], l);
                }
            }
            __syncthreads();
            if (tid == 0) {
                unsigned int remS = remSh;
                int nb = (int)maskv[pass] + 1;
                unsigned int cum = 0; float sAb = 0.0f; unsigned int bsel = 0;
                for (int bin = nb - 1; bin >= 0; --bin) {
                    unsigned int cc = hcnt[bin];
                    if (cum + cc >= remS) { bsel = (unsigned int)bin; break; }
                    cum += cc; sAb += hsum[bin];
                }
                selBin = bsel;
                remSh = remS - cum;
                sumTopSh += sAb;
            }
            __syncthreads();
            if (pass == 0) prefix = selBin;
            else if (pass == 1) prefix = (prefix << 11) | selBin;
            __syncthreads();
        }
        if (tid == 0) {
            unsigned int bits = (prefix << 10) | selBin;   // exact k-th largest
            float topk = sumTopSh + (float)remSh * __uint_as_float(bits);
            lossSh[s2] += topk / (float)max(k2, 1);
        }
        __syncthreads();
    }

    if (tid < NS) {
        float lossv = lossSh[tid];
        for (int off = 32; off > 0; off >>= 1) lossv += __shfl_down(lossv, off);
        if (tid == 0) out[0] = lossv / 32.0f;   // mean over B of (char + aff)
    }
}

extern "C" void kernel_launch(void* const* d_in, const int* in_sizes, int n_in,
                              void* d_out, int out_size, void* d_ws, size_t ws_size,
                              hipStream_t stream) {
    const float* x  = (const float*)d_in[0];
    const float* ct = (const float*)d_in[1];
    const float* at = (const float*)d_in[2];
    float* out = (float*)d_out;

    float* partA = (float*)d_ws;                 // NS*BPS floats
    float* partP = partA + NS * BPS;             // NS*BPS floats
    int*   partC = (int*)(partP + NS * BPS);     // NS*BPS ints

    k_reduce<<<dim3(NS * BPS), dim3(TPB), 0, stream>>>(x, ct, at, partA, partP, partC);
    k_tail<<<dim3(1), dim3(TPB), 0, stream>>>(x, ct, at, partA, partP, partC, out);
}